// Round 16
// baseline (97.253 us; speedup 1.0000x reference)
//
#include <hip/hip_runtime.h>
#include <hip/hip_bf16.h>

#define BATCH 8192
#define DIN   4096
#define H1    128
#define NLAT  512
#define LAT   32
#define BM    32
#define PP    130           // pacc pitch (ushorts)

typedef short bf16x8 __attribute__((ext_vector_type(8)));
typedef short bf16x4 __attribute__((ext_vector_type(4)));
typedef float f32x4  __attribute__((ext_vector_type(4)));

static __device__ __forceinline__ unsigned short f2bf(float f) {
  union { float f; unsigned u; } v; v.f = f;
  return (unsigned short)((v.u + 0x7FFFu + ((v.u >> 16) & 1u)) >> 16);  // RNE
}
static __device__ __forceinline__ float bf2f(unsigned short u) {
  union { unsigned u; float f; } v; v.u = ((unsigned)u) << 16; return v.f;
}

// ---- prep_all: W1 -> W1B frag-packed bf16 (1 MB); W2 -> W2B (128 KB);
// decoders -> decB frag-packed bf16 (256 KB). (byte-identical to R15) ----
__global__ void prep_all(const float* __restrict__ W1, const float* __restrict__ W2,
                         const float* __restrict__ dec,
                         unsigned short* __restrict__ W1B,
                         unsigned short* __restrict__ W2B,
                         unsigned short* __restrict__ decB) {
  int b = blockIdx.x;
  int t = threadIdx.x;
  int lane = t & 63;
  int g = lane >> 4, fr = lane & 15;
  if (b < 256) {
    int gi = (b << 2) + (t >> 6);
    int kb = ((gi >> 3) << 5) + (g << 3);
    int c = ((gi & 7) << 4) + fr;
    union { bf16x8 v; unsigned short u[8]; } o;
#pragma unroll
    for (int j = 0; j < 8; j++) o.u[j] = f2bf(W1[(size_t)(kb + j) * H1 + c]);
    *(bf16x8*)(W1B + (((size_t)gi << 6) + lane) * 8) = o.v;
  } else if (b < 288) {
    int gi = ((b - 256) << 2) + (t >> 6);
    int kb = ((gi >> 5) << 5) + (g << 3);
    int c = ((gi & 31) << 4) + fr;
    union { bf16x8 v; unsigned short u[8]; } o;
#pragma unroll
    for (int j = 0; j < 8; j++) o.u[j] = f2bf(W2[(size_t)(kb + j) * NLAT + c]);
    *(bf16x8*)(W2B + (((size_t)gi << 6) + lane) * 8) = o.v;
  } else {
    int cf = ((b - 288) << 2) + (t >> 6);       // 0..255 col-frags
    const float* src = dec + ((size_t)(cf * 16 + fr)) * LAT + (g << 3);
    union { bf16x8 v; unsigned short u[8]; } o;
#pragma unroll
    for (int j = 0; j < 8; j++) o.u[j] = f2bf(src[j]);
    *(bf16x8*)(decB + (((size_t)cf << 6) + lane) * 8) = o.v;
  }
}

// ---- enc_kernel: R14's BM=32 kernel with __launch_bounds__(512,2) — the
// single change vs R14 (VGPR cap 256, no spill). B L2 traffic halved vs
// BM=16 (512 -> 256 MB). Phase A reg-direct barrier-free, 8 waves,
// wave-private K=512, 32 rows per wave per B-fragment load. ----
__global__ __launch_bounds__(512, 2) void enc_kernel(
    const float* __restrict__ x, const unsigned short* __restrict__ W1B,
    const unsigned short* __restrict__ W2B,
    const float* __restrict__ b1, const float* __restrict__ b2,
    float* __restrict__ zout, unsigned short* __restrict__ zsumb) {
  // [0, 66560): pacc bf16 [8][32][PP]; zsp f32 [8][16][33] aliases [0,16896)
  // [66560, 74752): hs bf16 [32][128] XOR-swizzled
  __shared__ __align__(16) unsigned char smem[74752];
  unsigned short* pacc = (unsigned short*)smem;
  unsigned short* hs   = (unsigned short*)(smem + 66560);
  float* zsp           = (float*)smem;

  const int t = threadIdx.x;
  const int rbase = blockIdx.x << 5;
  const int w = t >> 6, lane = t & 63;
  const int g = lane >> 4, fr = lane & 15;

  // ---- phase A: reg-direct, barrier-free. Wave w: K in [w*512, +512). ----
  f32x4 acc0[8], acc1[8];
#pragma unroll
  for (int i = 0; i < 8; i++) {
    acc0[i] = (f32x4){0.f, 0.f, 0.f, 0.f};
    acc1[i] = (f32x4){0.f, 0.f, 0.f, 0.f};
  }
  const float* arow0 = x + (size_t)(rbase + fr) * DIN + (w << 9) + (g << 3);
  const float* arow1 = arow0 + ((size_t)DIN << 4);   // +16 rows
#pragma unroll 2
  for (int c = 0; c < 16; ++c) {
    f32x4 a0 = *(const f32x4*)(arow0 + (c << 5));
    f32x4 a1 = *(const f32x4*)(arow0 + (c << 5) + 4);
    f32x4 a2 = *(const f32x4*)(arow1 + (c << 5));
    f32x4 a3 = *(const f32x4*)(arow1 + (c << 5) + 4);
    union { bf16x8 v; unsigned short u[8]; } af0, af1;
#pragma unroll
    for (int j = 0; j < 4; j++) {
      af0.u[j] = f2bf(a0[j]); af0.u[4 + j] = f2bf(a1[j]);
      af1.u[j] = f2bf(a2[j]); af1.u[4 + j] = f2bf(a3[j]);
    }
    const unsigned short* bp =
        W1B + (((size_t)((w << 4) + c) << 3) << 9) + (lane << 3);
#pragma unroll
    for (int cf = 0; cf < 8; ++cf) {
      bf16x8 bv = *(const bf16x8*)(bp + ((size_t)cf << 9));
      acc0[cf] = __builtin_amdgcn_mfma_f32_16x16x32_bf16(af0.v, bv, acc0[cf], 0, 0, 0);
      acc1[cf] = __builtin_amdgcn_mfma_f32_16x16x32_bf16(af1.v, bv, acc1[cf], 0, 0, 0);
    }
  }

  // partials -> pacc bf16. C/D: col=fr, row=g*4+j (acc0: rows 0-15, acc1: +16)
#pragma unroll
  for (int cf = 0; cf < 8; ++cf)
#pragma unroll
    for (int j = 0; j < 4; ++j) {
      pacc[(w * BM + (g << 2) + j) * PP + (cf << 4) + fr] = f2bf(acc0[cf][j]);
      pacc[(w * BM + 16 + (g << 2) + j) * PP + (cf << 4) + fr] = f2bf(acc1[cf][j]);
    }
  __syncthreads();

  // reduce 8 partials + b1 + relu -> hs (bf16, XOR-swizzled granules).
  // 512 thr: 16/row, 8 cols each.
  {
    const int r = t >> 4, c8 = (t & 15) << 3;
    f32x4 s0 = *(const f32x4*)(b1 + c8);
    f32x4 s1 = *(const f32x4*)(b1 + c8 + 4);
#pragma unroll
    for (int wv = 0; wv < 8; ++wv) {
      union { bf16x8 v; unsigned short u[8]; } p;
      p.v = *(const bf16x8*)&pacc[(wv * BM + r) * PP + c8];
#pragma unroll
      for (int j = 0; j < 4; j++) { s0[j] += bf2f(p.u[j]); s1[j] += bf2f(p.u[4 + j]); }
    }
    union { bf16x8 v; unsigned short u[8]; } o;
#pragma unroll
    for (int j = 0; j < 4; j++) {
      o.u[j] = f2bf(fmaxf(s0[j], 0.f));
      o.u[4 + j] = f2bf(fmaxf(s1[j], 0.f));
    }
    const int gi = t & 15;
    *(bf16x8*)(hs + (r << 7) + ((gi ^ (r & 15)) << 3)) = o.v;
  }
  __syncthreads();

  // ---- phase B: z = h@W2+b2. Wave (wr=w&1, wc=w>>1): rows wr*16..+16,
  // cols wc*128..+128. ----
  const int wr = w & 1, wc = w >> 1;
  f32x4 acc2[8];
#pragma unroll
  for (int i = 0; i < 8; i++) acc2[i] = (f32x4){0.f, 0.f, 0.f, 0.f};
#pragma unroll
  for (int k32 = 0; k32 < 4; ++k32) {
    bf16x8 a0 = *(const bf16x8*)(hs + (((wr << 4) + fr) << 7) +
                  ((((k32 << 2) + g) ^ fr) << 3));
#pragma unroll
    for (int cc = 0; cc < 8; ++cc) {
      bf16x8 bv = *(const bf16x8*)(W2B +
          (((size_t)((k32 << 5) + (wc << 3) + cc)) << 9) + (lane << 3));
      acc2[cc] = __builtin_amdgcn_mfma_f32_16x16x32_bf16(a0, bv, acc2[cc], 0, 0, 0);
    }
  }
  // z write + zsum fold. col = wc*128+cc*16+fr; latent=(cc&1)*16+fr.
  {
    f32x4 zv[8];
#pragma unroll
    for (int cc = 0; cc < 8; ++cc) {
      const float b2v = b2[(wc << 7) + (cc << 4) + fr];
#pragma unroll
      for (int j = 0; j < 4; j++) zv[cc][j] = acc2[cc][j] + b2v;
    }
    const int row0 = g << 2;
#pragma unroll
    for (int j = 0; j < 4; j++) {
      const int grow = rbase + (wr << 4) + row0 + j;
#pragma unroll
      for (int cc = 0; cc < 8; ++cc)
        zout[(size_t)grow * NLAT + (wc << 7) + (cc << 4) + fr] = zv[cc][j];
      zsp[(w * 16 + row0 + j) * 33 + fr]      = zv[0][j] + zv[2][j] + zv[4][j] + zv[6][j];
      zsp[(w * 16 + row0 + j) * 33 + 16 + fr] = zv[1][j] + zv[3][j] + zv[5][j] + zv[7][j];
    }
  }
  __syncthreads();
  // reduce 4 col-wave partials -> zsumb bf16 (1024 entries, 512 thr x 2)
#pragma unroll
  for (int i = 0; i < 2; i++) {
    const int idx = t + (i << 9);
    const int r = idx >> 5, l = idx & 31;   // r 0..31
    const int rh = r >> 4;
    float s = 0.f;
#pragma unroll
    for (int wcv = 0; wcv < 4; ++wcv)
      s += zsp[(((wcv << 1) | rh) * 16 + (r & 15)) * 33 + l];
    zsumb[(size_t)(rbase + r) * LAT + l] = f2bf(s);
  }
}

// ---- recon_kernel (MFMA streaming, byte-identical to R15): rout = zsumb @ decB. ----
__global__ __launch_bounds__(256) void recon_kernel(
    const unsigned short* __restrict__ zsumb, const unsigned short* __restrict__ decB,
    float* __restrict__ rout) {
  const int t = threadIdx.x;
  const int w = t >> 6, lane = t & 63;
  const int g = lane >> 4, fr = lane & 15;
  const int rbase = (blockIdx.x >> 2) << 4;
  const int cf0 = ((blockIdx.x & 3) << 6) + (w << 4);

  bf16x8 af = *(const bf16x8*)(zsumb + (size_t)(rbase + fr) * LAT + (g << 3));
  const f32x4 zero = (f32x4){0.f, 0.f, 0.f, 0.f};
#pragma unroll 4
  for (int f = 0; f < 16; ++f) {
    const int cf = cf0 + f;
    bf16x8 bv = *(const bf16x8*)(decB + (((size_t)cf << 6) + lane) * 8);
    f32x4 c = __builtin_amdgcn_mfma_f32_16x16x32_bf16(af, bv, zero, 0, 0, 0);
#pragma unroll
    for (int j = 0; j < 4; j++)
      rout[(size_t)(rbase + (g << 2) + j) * DIN + (cf << 4) + fr] = c[j];
  }
}

extern "C" void kernel_launch(void* const* d_in, const int* in_sizes, int n_in,
                              void* d_out, int out_size, void* d_ws, size_t ws_size,
                              hipStream_t stream) {
  const float* x   = (const float*)d_in[0];
  const float* W1  = (const float*)d_in[1];
  const float* b1  = (const float*)d_in[2];
  const float* W2  = (const float*)d_in[3];
  const float* b2  = (const float*)d_in[4];
  const float* dec = (const float*)d_in[5];
  float* zout = (float*)d_out;
  float* rout = zout + (size_t)BATCH * NLAT;

  char* ws = (char*)d_ws;
  unsigned short* W1B   = (unsigned short*)ws;                               // 1 MB
  unsigned short* W2B   = (unsigned short*)(ws + (1u << 20));                // 128 KB
  unsigned short* decB  = (unsigned short*)(ws + (1u << 20) + (128u << 10)); // 256 KB
  unsigned short* zsumb = (unsigned short*)(ws + (1u << 20) + (384u << 10)); // 512 KB

  prep_all<<<dim3(352), 256, 0, stream>>>(W1, W2, dec, W1B, W2B, decB);
  enc_kernel<<<dim3(BATCH / BM), 512, 0, stream>>>(x, W1B, W2B, b1, b2, zout, zsumb);
  recon_kernel<<<dim3(2048), 256, 0, stream>>>(zsumb, decB, rout);
}

// Round 17
// 84.675 us; speedup vs baseline: 1.1485x; 1.1485x over previous
//
#include <hip/hip_runtime.h>
#include <hip/hip_bf16.h>

#define BATCH 8192
#define DIN   4096
#define H1    128
#define NLAT  512
#define LAT   32
#define BM    16
#define PP    130           // pacc pitch (ushorts)

typedef short bf16x8 __attribute__((ext_vector_type(8)));
typedef short bf16x4 __attribute__((ext_vector_type(4)));
typedef float f32x4  __attribute__((ext_vector_type(4)));
typedef float f32x16 __attribute__((ext_vector_type(16)));

static __device__ __forceinline__ unsigned short f2bf(float f) {
  union { float f; unsigned u; } v; v.f = f;
  return (unsigned short)((v.u + 0x7FFFu + ((v.u >> 16) & 1u)) >> 16);  // RNE
}
static __device__ __forceinline__ float bf2f(unsigned short u) {
  union { unsigned u; float f; } v; v.u = ((unsigned)u) << 16; return v.f;
}

// ---- prep_all: W1 -> W1B frag-packed bf16 (1 MB); W2 -> W2B (128 KB);
// decoders -> decB32: 32x32x16-MFMA fragment layout (256 KB).
// decB32[((cf*2+q)*64 + lane)*8 + j] = bf16(B[k = q*16 + (lane>>5)*8 + j]
//   [n = cf*32 + (lane&31)]) where B[k][n] = dec_flat[n][k]. ----
__global__ void prep_all(const float* __restrict__ W1, const float* __restrict__ W2,
                         const float* __restrict__ dec,
                         unsigned short* __restrict__ W1B,
                         unsigned short* __restrict__ W2B,
                         unsigned short* __restrict__ decB) {
  int b = blockIdx.x;
  int t = threadIdx.x;
  int lane = t & 63;
  if (b < 256) {
    int g = lane >> 4, fr = lane & 15;
    int gi = (b << 2) + (t >> 6);
    int kb = ((gi >> 3) << 5) + (g << 3);
    int c = ((gi & 7) << 4) + fr;
    union { bf16x8 v; unsigned short u[8]; } o;
#pragma unroll
    for (int j = 0; j < 8; j++) o.u[j] = f2bf(W1[(size_t)(kb + j) * H1 + c]);
    *(bf16x8*)(W1B + (((size_t)gi << 6) + lane) * 8) = o.v;
  } else if (b < 288) {
    int g = lane >> 4, fr = lane & 15;
    int gi = ((b - 256) << 2) + (t >> 6);
    int kb = ((gi >> 5) << 5) + (g << 3);
    int c = ((gi & 31) << 4) + fr;
    union { bf16x8 v; unsigned short u[8]; } o;
#pragma unroll
    for (int j = 0; j < 8; j++) o.u[j] = f2bf(W2[(size_t)(kb + j) * NLAT + c]);
    *(bf16x8*)(W2B + (((size_t)gi << 6) + lane) * 8) = o.v;
  } else {
    // decB32: group = (b-288)*4 + wave = cf*2 + q, cf 0..127, q 0..1
    int grp = ((b - 288) << 2) + (t >> 6);
    int cf = grp >> 1, q = grp & 1;
    int m = lane & 31, h = lane >> 5;
    const float* src = dec + ((size_t)(cf * 32 + m)) * LAT + q * 16 + h * 8;
    union { bf16x8 v; unsigned short u[8]; } o;
#pragma unroll
    for (int j = 0; j < 8; j++) o.u[j] = f2bf(src[j]);
    *(bf16x8*)(decB + (((size_t)grp << 6) + lane) * 8) = o.v;
  }
}

// ---- enc_kernel: BYTE-IDENTICAL to R15's measured kernel (BM=16,
// reg-direct barrier-free phase A, 16 waves/CU). ----
__global__ __launch_bounds__(512, 2) void enc_kernel(
    const float* __restrict__ x, const unsigned short* __restrict__ W1B,
    const unsigned short* __restrict__ W2B,
    const float* __restrict__ b1, const float* __restrict__ b2,
    float* __restrict__ zout, unsigned short* __restrict__ zsumb) {
  __shared__ unsigned short pacc[8 * BM * PP];   // 33.3 KB bf16 partials
  __shared__ unsigned short hs[16 * 128];        // 4 KB, XOR-swizzled
  __shared__ float zsp[8 * BM * 33];             // 16.9 KB

  const int t = threadIdx.x;
  const int rbase = blockIdx.x << 4;
  const int w = t >> 6, lane = t & 63;
  const int g = lane >> 4, fr = lane & 15;

  f32x4 acc[8];
#pragma unroll
  for (int i = 0; i < 8; i++) acc[i] = (f32x4){0.f, 0.f, 0.f, 0.f};

  const float* arow = x + (size_t)(rbase + fr) * DIN + (w << 9) + (g << 3);
#pragma unroll 4
  for (int c = 0; c < 16; ++c) {
    f32x4 a0 = *(const f32x4*)(arow + (c << 5));
    f32x4 a1 = *(const f32x4*)(arow + (c << 5) + 4);
    union { bf16x8 v; unsigned short u[8]; } af;
#pragma unroll
    for (int j = 0; j < 4; j++) { af.u[j] = f2bf(a0[j]); af.u[4 + j] = f2bf(a1[j]); }
    const unsigned short* bp =
        W1B + (((size_t)((w << 4) + c) << 3) << 9) + (lane << 3);
#pragma unroll
    for (int cf = 0; cf < 8; ++cf) {
      bf16x8 bv = *(const bf16x8*)(bp + ((size_t)cf << 9));
      acc[cf] = __builtin_amdgcn_mfma_f32_16x16x32_bf16(af.v, bv, acc[cf], 0, 0, 0);
    }
  }

#pragma unroll
  for (int cf = 0; cf < 8; ++cf)
#pragma unroll
    for (int j = 0; j < 4; ++j)
      pacc[(w * BM + (g << 2) + j) * PP + (cf << 4) + fr] = f2bf(acc[cf][j]);
  __syncthreads();

  {
    const int r = t >> 5, c4 = (t & 31) << 2;
    float s0 = b1[c4], s1 = b1[c4 + 1], s2 = b1[c4 + 2], s3 = b1[c4 + 3];
#pragma unroll
    for (int wv = 0; wv < 8; ++wv) {
      union { bf16x4 v; unsigned short u[4]; } p;
      p.v = *(const bf16x4*)&pacc[(wv * BM + r) * PP + c4];
      s0 += bf2f(p.u[0]); s1 += bf2f(p.u[1]); s2 += bf2f(p.u[2]); s3 += bf2f(p.u[3]);
    }
    union { bf16x4 v; unsigned short u[4]; } o;
    o.u[0] = f2bf(fmaxf(s0, 0.f)); o.u[1] = f2bf(fmaxf(s1, 0.f));
    o.u[2] = f2bf(fmaxf(s2, 0.f)); o.u[3] = f2bf(fmaxf(s3, 0.f));
    const int gi = c4 >> 3;
    *(bf16x4*)(hs + (r << 7) + ((gi ^ (r & 15)) << 3) + (c4 & 7)) = o.v;
  }
  __syncthreads();

  f32x4 acc2[4];
#pragma unroll
  for (int i = 0; i < 4; i++) acc2[i] = (f32x4){0.f, 0.f, 0.f, 0.f};
#pragma unroll
  for (int k32 = 0; k32 < 4; ++k32) {
    bf16x8 a0 = *(const bf16x8*)(hs + (fr << 7) +
                  ((((k32 << 2) + g) ^ (fr & 15)) << 3));
#pragma unroll
    for (int cc = 0; cc < 4; ++cc) {
      bf16x8 bv = *(const bf16x8*)(W2B +
          (((size_t)((k32 << 5) + (w << 2) + cc)) << 9) + (lane << 3));
      acc2[cc] = __builtin_amdgcn_mfma_f32_16x16x32_bf16(a0, bv, acc2[cc], 0, 0, 0);
    }
  }
  {
    f32x4 zv[4];
#pragma unroll
    for (int cc = 0; cc < 4; ++cc) {
      const float b2v = b2[(w << 6) + (cc << 4) + fr];
#pragma unroll
      for (int j = 0; j < 4; j++) zv[cc][j] = acc2[cc][j] + b2v;
    }
    const int row0 = g << 2;
#pragma unroll
    for (int j = 0; j < 4; j++) {
#pragma unroll
      for (int cc = 0; cc < 4; ++cc)
        zout[(size_t)(rbase + row0 + j) * NLAT + (w << 6) + (cc << 4) + fr] = zv[cc][j];
      zsp[(w * BM + row0 + j) * 33 + fr]      = zv[0][j] + zv[2][j];
      zsp[(w * BM + row0 + j) * 33 + 16 + fr] = zv[1][j] + zv[3][j];
    }
  }
  __syncthreads();
  {
    const int r = t >> 5, l = t & 31;
    float s = 0.f;
#pragma unroll
    for (int wv = 0; wv < 8; ++wv) s += zsp[(wv * BM + r) * 33 + l];
    zsumb[(size_t)(rbase + r) * LAT + l] = f2bf(s);
  }
}

// ---- recon_kernel (32x32x16 MFMA): rout = zsumb @ decB32.
// K=32 = two chained 32x32x16 MFMAs. C/D layout (HW-verified m74/m101):
// col = lane&31, row = (reg&3) + 8*(reg>>2) + 4*(lane>>5) -> every store
// inst covers 2 full 128B lines (32 lanes x 4B x 2 rows). Block: 32 rows x
// 1024 cols, 4 waves x 8 col-frags; A-frags loaded once per wave. ----
__global__ __launch_bounds__(256) void recon_kernel(
    const unsigned short* __restrict__ zsumb, const unsigned short* __restrict__ decB,
    float* __restrict__ rout) {
  const int t = threadIdx.x;
  const int w = t >> 6, lane = t & 63;
  const int m = lane & 31, h = lane >> 5;
  const int rbase = (blockIdx.x >> 2) << 5;
  const int cfbase = ((blockIdx.x & 3) << 5) + (w << 3);

  const unsigned short* arow = zsumb + ((size_t)(rbase + m) << 5) + (h << 3);
  bf16x8 a0 = *(const bf16x8*)(arow);        // k = h*8 + j
  bf16x8 a1 = *(const bf16x8*)(arow + 16);   // k = 16 + h*8 + j

#pragma unroll 2
  for (int f = 0; f < 8; ++f) {
    const int cf = cfbase + f;
    bf16x8 bv0 = *(const bf16x8*)(decB + ((size_t)cf << 10) + (lane << 3));
    bf16x8 bv1 = *(const bf16x8*)(decB + ((size_t)cf << 10) + 512 + (lane << 3));
    f32x16 c;
#pragma unroll
    for (int i = 0; i < 16; ++i) c[i] = 0.f;
    c = __builtin_amdgcn_mfma_f32_32x32x16_bf16(a0, bv0, c, 0, 0, 0);
    c = __builtin_amdgcn_mfma_f32_32x32x16_bf16(a1, bv1, c, 0, 0, 0);
    const int colbase = (cf << 5) + m;
#pragma unroll
    for (int r = 0; r < 16; ++r) {
      const int row = rbase + (r & 3) + ((r >> 2) << 3) + (h << 2);
      rout[(size_t)row * DIN + colbase] = c[r];
    }
  }
}

extern "C" void kernel_launch(void* const* d_in, const int* in_sizes, int n_in,
                              void* d_out, int out_size, void* d_ws, size_t ws_size,
                              hipStream_t stream) {
  const float* x   = (const float*)d_in[0];
  const float* W1  = (const float*)d_in[1];
  const float* b1  = (const float*)d_in[2];
  const float* W2  = (const float*)d_in[3];
  const float* b2  = (const float*)d_in[4];
  const float* dec = (const float*)d_in[5];
  float* zout = (float*)d_out;
  float* rout = zout + (size_t)BATCH * NLAT;

  char* ws = (char*)d_ws;
  unsigned short* W1B   = (unsigned short*)ws;                               // 1 MB
  unsigned short* W2B   = (unsigned short*)(ws + (1u << 20));                // 128 KB
  unsigned short* decB  = (unsigned short*)(ws + (1u << 20) + (128u << 10)); // 256 KB
  unsigned short* zsumb = (unsigned short*)(ws + (1u << 20) + (384u << 10)); // 512 KB

  prep_all<<<dim3(352), 256, 0, stream>>>(W1, W2, dec, W1B, W2B, decB);
  enc_kernel<<<dim3(BATCH / BM), 512, 0, stream>>>(x, W1B, W2B, b1, b2, zout, zsumb);
  recon_kernel<<<dim3(1024), 256, 0, stream>>>(zsumb, decB, rout);
}